// Round 13
// baseline (79.214 us; speedup 1.0000x reference)
//
#include <hip/hip_runtime.h>
#include <hip/hip_bf16.h>

// Problem dims (fixed by reference)
#define N_IN   1024     // K
#define N_P    1024     // N (= 32*32 lifted grid)
#define FILT   33
#define PAD    16

typedef __attribute__((ext_vector_type(8))) __bf16 bf16x8;
typedef __attribute__((ext_vector_type(4))) float  f32x4;

#define GLB(p) ((const __attribute__((address_space(1))) unsigned int*)(p))
#define LDSP(p) ((__attribute__((address_space(3))) unsigned int*)(p))

__device__ __forceinline__ unsigned short f2bf(float f) {
    union { __hip_bfloat16 h; unsigned short u; } cv;
    cv.h = __float2bfloat16(f);
    return cv.u;
}

// ---------------------------------------------------------------------------
// Kernel 1: per-row demean + std-normalize, fp32 -> bf16 (r1-proven, ~BW floor)
// ---------------------------------------------------------------------------
__global__ __launch_bounds__(256)
void normalize_kernel(const float* __restrict__ x, __hip_bfloat16* __restrict__ xn)
{
    const int lane = threadIdx.x & 63;
    const int row  = blockIdx.x * 4 + (threadIdx.x >> 6);

    const float4* xr = reinterpret_cast<const float4*>(x + (size_t)row * N_IN);
    float4 v[4];
    float s = 0.f, s2 = 0.f;
#pragma unroll
    for (int i = 0; i < 4; i++) {
        v[i] = xr[i * 64 + lane];
        s  += v[i].x + v[i].y + v[i].z + v[i].w;
        s2 += v[i].x * v[i].x + v[i].y * v[i].y + v[i].z * v[i].z + v[i].w * v[i].w;
    }
#pragma unroll
    for (int off = 32; off > 0; off >>= 1) {
        s  += __shfl_xor(s,  off, 64);
        s2 += __shfl_xor(s2, off, 64);
    }
    const float mu  = s * (1.0f / N_IN);
    const float var = fmaxf(s2 * (1.0f / N_IN) - mu * mu, 0.0f);
    const float inv = 1.0f / (sqrtf(var) + 1e-7f);

    ushort4* outv = reinterpret_cast<ushort4*>(xn + (size_t)row * N_IN);
#pragma unroll
    for (int i = 0; i < 4; i++) {
        ushort4 o;
        o.x = f2bf((v[i].x - mu) * inv);
        o.y = f2bf((v[i].y - mu) * inv);
        o.z = f2bf((v[i].z - mu) * inv);
        o.w = f2bf((v[i].w - mu) * inv);
        outv[i * 64 + lane] = o;
    }
}

// ---------------------------------------------------------------------------
// Kernel 2: Gaussian resolution filter + circular conv along n, fp32 -> bf16
// ---------------------------------------------------------------------------
__global__ __launch_bounds__(256)
void conv_kernel(const float* __restrict__ lm_raw, __hip_bfloat16* __restrict__ lm)
{
    __shared__ float row[N_IN];
    __shared__ float fw[FILT];
    const int tid = threadIdx.x;
    const int p   = blockIdx.x;

    if (tid < FILT) {
        float t = (tid - PAD) * (2.0f / FILT);
        float u = t * 10.0f;            // t / sigma0 (sigma0 = 0.1)
        fw[tid] = expf(-0.5f * u * u);
    }
    reinterpret_cast<float4*>(row)[tid] =
        reinterpret_cast<const float4*>(lm_raw + (size_t)p * N_IN)[tid];
    __syncthreads();

    float fsum = 0.f;
#pragma unroll
    for (int f = 0; f < FILT; f++) fsum += fw[f];
    const float inv = 1.0f / fsum;

    const int n0 = tid * 4;
    float o[4] = {0.f, 0.f, 0.f, 0.f};
#pragma unroll
    for (int f = 0; f < FILT; f++) {
        const float w = fw[f];
#pragma unroll
        for (int j = 0; j < 4; j++)
            o[j] += w * row[(n0 + j + f - PAD) & (N_IN - 1)];
    }
    ushort4 ov;
    ov.x = f2bf(o[0] * inv);
    ov.y = f2bf(o[1] * inv);
    ov.z = f2bf(o[2] * inv);
    ov.w = f2bf(o[3] * inv);
    reinterpret_cast<ushort4*>(lm + (size_t)p * N_IN)[tid] = ov;
}

// ---------------------------------------------------------------------------
// Kernel 3: GEMM  C[M,N] = A[M,K] * B[N,K]^T  — B-from-L2-registers variant.
// 256x256 tile, BK=32, 512 thr (8 waves 2Mx4N), per-wave 128x64 (acc[8][4]).
// A: LDS 3-ring (3 x 16KB), global_load_lds, pre-swizzled source,
//    counted vmcnt (A(t) guaranteed by vmcnt(6): younger = A(t+1):2 + B:4).
// B: NO LDS — each lane loads its bf16x8 fragment straight from global
//    (col*2048 + t*64 + kb*16; 16 x 64B segments/wave-instr, L2-resident
//    512KB panel). Register-double-buffered via unroll-2 (static indexing);
//    completion ordered by compiler auto-vmcnt on register use. B rides the
//    VMEM pipe -> overlaps MFMA/LDS, free of barrier lockstep (m114).
// Removes 33% of LDS reads + all B staging writes from the LDS pipe.
// ---------------------------------------------------------------------------
__global__ __launch_bounds__(512, 2)
void gemm_breg(const __hip_bfloat16* __restrict__ A,
               const __hip_bfloat16* __restrict__ B,
               float* __restrict__ C,
               int M, int N, int K)
{
    constexpr int BK = 32;                  // K-tile; A rows are 64B in LDS
    __shared__ char As[3][16384];           // ring: A[256 rows][64 B]

    const int tid = threadIdx.x;
    const int l   = tid & 63;
    const int w   = tid >> 6;    // 0..7
    const int wm  = w >> 2;      // 0..1  (M direction, 128 rows)
    const int wn  = w & 3;       // 0..3  (N direction, 64 cols)

    // T1: bijective XCD swizzle (nwg=256 divisible by 8)
    const int o    = blockIdx.x;
    const int lin  = (o & 7) * (gridDim.x >> 3) + (o >> 3);
    const int tn   = lin & 3;          // N/256 = 4
    const int tm   = lin >> 2;         // M/256 = 64
    const size_t bm = (size_t)tm * 256;
    const size_t bn = (size_t)tn * 256;

    // ---- A staging geometry (r11-identical): 2 gloads = 256 rows x 64B ----
    const int srow = w * 16 + (l >> 2);
    const int scol = 16 * ((l & 3) ^ ((l >> 3) & 3));
    const char* gA = (const char*)(A + (bm + srow) * (size_t)K) + scol;
    const size_t rowstep = (size_t)128 * K * 2;     // +128 rows (bytes)

#define STAGE_A(t, b) do {                                                      \
    const char* a0_ = gA + (size_t)(t) * (BK * 2);                              \
    char* La_ = &As[(b)][0] + w * 1024;                                         \
    __builtin_amdgcn_global_load_lds(GLB(a0_),           LDSP(La_),        16, 0, 0); \
    __builtin_amdgcn_global_load_lds(GLB(a0_ + rowstep), LDSP(La_ + 8192), 16, 0, 0); \
} while (0)

    // ---- A fragment-read geometry (swizzled ds_read, r11-identical) ----
    const int lr = l & 15;
    const int kb = l >> 4;                               // 16B k-slot
    const int rslot = 16 * (kb ^ ((lr >> 1) & 3));
    const int abase = (wm * 128 + lr) * 64 + rslot;      // + m*1024

    // ---- B direct-global geometry: lane reads B[bn+wn*64+n*16+lr][k] ----
    // bytes: col*2048 + n*32768 + t*64 + kb*16
    const char* gBr = (const char*)B + ((size_t)(bn + wn * 64 + lr)) * 2048 + kb * 16;

#define LOADB(dst, t) do {                                                      \
    _Pragma("unroll")                                                           \
    for (int n_ = 0; n_ < 4; n_++)                                              \
        dst[n_] = *(const bf16x8*)(gBr + n_ * 32768 + (size_t)(t) * 64);        \
} while (0)

#define BAR() do { asm volatile("" ::: "memory");                  \
                   __builtin_amdgcn_s_barrier();                   \
                   asm volatile("" ::: "memory"); } while (0)

    f32x4 acc[8][4] = {};
    const int NT = K / BK;                               // 32 (even)

    // prologue: A(0), A(1) staged; B(0) in regs
    STAGE_A(0, 0);
    STAGE_A(1, 1);
    bf16x8 rB0[4], rB1[4];
    LOADB(rB0, 0);

    for (int t = 0; t < NT; t += 2) {
        // ===== even sub-iter: consumes rB0(t), loads rB1(t+1) =====
        asm volatile("s_waitcnt lgkmcnt(0)" ::: "memory");  // my t-1 ds_reads drained
        asm volatile("s_waitcnt vmcnt(6)" ::: "memory");    // A(t) in LDS
        BAR();
        if (t + 2 < NT) STAGE_A(t + 2, (t + 2) % 3);
        LOADB(rB1, t + 1);                                  // t+1 <= 31 always
        {
            const char* Sa = &As[t % 3][0];
            bf16x8 afr[8];
#pragma unroll
            for (int m = 0; m < 8; m++) afr[m] = *(const bf16x8*)(Sa + abase + m * 1024);
            __builtin_amdgcn_s_setprio(1);
#pragma unroll
            for (int m = 0; m < 8; m++)
#pragma unroll
                for (int n = 0; n < 4; n++)
                    acc[m][n] = __builtin_amdgcn_mfma_f32_16x16x32_bf16(afr[m], rB0[n], acc[m][n], 0, 0, 0);
            __builtin_amdgcn_s_setprio(0);
        }

        // ===== odd sub-iter: consumes rB1(t+1), loads rB0(t+2) =====
        asm volatile("s_waitcnt lgkmcnt(0)" ::: "memory");
        if (t + 1 < NT - 1) asm volatile("s_waitcnt vmcnt(6)" ::: "memory"); // A(t+1) in LDS
        else                asm volatile("s_waitcnt vmcnt(4)" ::: "memory"); // tail: only A+B(t+1) pending
        BAR();
        if (t + 3 < NT) STAGE_A(t + 3, (t + 3) % 3);
        if (t + 2 < NT) LOADB(rB0, t + 2);
        {
            const char* Sa = &As[(t + 1) % 3][0];
            bf16x8 afr[8];
#pragma unroll
            for (int m = 0; m < 8; m++) afr[m] = *(const bf16x8*)(Sa + abase + m * 1024);
            __builtin_amdgcn_s_setprio(1);
#pragma unroll
            for (int m = 0; m < 8; m++)
#pragma unroll
                for (int n = 0; n < 4; n++)
                    acc[m][n] = __builtin_amdgcn_mfma_f32_16x16x32_bf16(afr[m], rB1[n], acc[m][n], 0, 0, 0);
            __builtin_amdgcn_s_setprio(0);
        }
    }
#undef STAGE_A
#undef LOADB
#undef BAR

    // epilogue: C/D layout col = lane&15, row = (lane>>4)*4 + reg  [m89/m91]
    const int crow = (l >> 4) * 4;
    const int ccol = l & 15;
#pragma unroll
    for (int m = 0; m < 8; m++)
#pragma unroll
        for (int n = 0; n < 4; n++) {
#pragma unroll
            for (int r = 0; r < 4; r++) {
                const size_t row = bm + wm * 128 + m * 16 + crow + r;
                const size_t col = bn + wn * 64 + n * 16 + ccol;
                C[row * N + col] = acc[m][n][r];
            }
        }
}

// ---------------------------------------------------------------------------
extern "C" void kernel_launch(void* const* d_in, const int* in_sizes, int n_in,
                              void* d_out, int out_size, void* d_ws, size_t ws_size,
                              hipStream_t stream) {
    const float* x      = (const float*)d_in[0];   // [M, 1024] fp32
    const float* lm_raw = (const float*)d_in[1];   // [32, 32, 1024] fp32
    float* out = (float*)d_out;                    // [M, 32, 32] fp32

    const int M = in_sizes[0] / N_IN;              // 16384

    // workspace layout: xn bf16 [M,1024] (32 MiB) | lm bf16 [1024,1024] (2 MiB)
    __hip_bfloat16* xn = (__hip_bfloat16*)d_ws;
    __hip_bfloat16* lm = (__hip_bfloat16*)((char*)d_ws + (size_t)M * N_IN * 2);

    normalize_kernel<<<M / 4, 256, 0, stream>>>(x, xn);
    conv_kernel<<<N_P, 256, 0, stream>>>(lm_raw, lm);

    const int nblk = (M / 256) * (N_P / 256);      // 64 * 4 = 256
    gemm_breg<<<nblk, dim3(512), 0, stream>>>(xn, lm, out, M, N_P, N_IN);
}

// Round 14
// 65.626 us; speedup vs baseline: 1.2071x; 1.2071x over previous
//
#include <hip/hip_runtime.h>
#include <hip/hip_bf16.h>

// Problem dims (fixed by reference)
#define N_IN   1024     // K
#define N_P    1024     // N (= 32*32 lifted grid)
#define FILT   33
#define PAD    16

typedef __attribute__((ext_vector_type(8))) __bf16 bf16x8;
typedef __attribute__((ext_vector_type(4))) float  f32x4;

#define GLB(p) ((const __attribute__((address_space(1))) unsigned int*)(p))
#define LDSP(p) ((__attribute__((address_space(3))) unsigned int*)(p))

__device__ __forceinline__ unsigned short f2bf(float f) {
    union { __hip_bfloat16 h; unsigned short u; } cv;
    cv.h = __float2bfloat16(f);
    return cv.u;
}

// ---------------------------------------------------------------------------
// Kernel 1: per-row demean + std-normalize, fp32 -> bf16 (r1-proven, ~BW floor)
// ---------------------------------------------------------------------------
__global__ __launch_bounds__(256)
void normalize_kernel(const float* __restrict__ x, __hip_bfloat16* __restrict__ xn)
{
    const int lane = threadIdx.x & 63;
    const int row  = blockIdx.x * 4 + (threadIdx.x >> 6);

    const float4* xr = reinterpret_cast<const float4*>(x + (size_t)row * N_IN);
    float4 v[4];
    float s = 0.f, s2 = 0.f;
#pragma unroll
    for (int i = 0; i < 4; i++) {
        v[i] = xr[i * 64 + lane];
        s  += v[i].x + v[i].y + v[i].z + v[i].w;
        s2 += v[i].x * v[i].x + v[i].y * v[i].y + v[i].z * v[i].z + v[i].w * v[i].w;
    }
#pragma unroll
    for (int off = 32; off > 0; off >>= 1) {
        s  += __shfl_xor(s,  off, 64);
        s2 += __shfl_xor(s2, off, 64);
    }
    const float mu  = s * (1.0f / N_IN);
    const float var = fmaxf(s2 * (1.0f / N_IN) - mu * mu, 0.0f);
    const float inv = 1.0f / (sqrtf(var) + 1e-7f);

    ushort4* outv = reinterpret_cast<ushort4*>(xn + (size_t)row * N_IN);
#pragma unroll
    for (int i = 0; i < 4; i++) {
        ushort4 o;
        o.x = f2bf((v[i].x - mu) * inv);
        o.y = f2bf((v[i].y - mu) * inv);
        o.z = f2bf((v[i].z - mu) * inv);
        o.w = f2bf((v[i].w - mu) * inv);
        outv[i * 64 + lane] = o;
    }
}

// ---------------------------------------------------------------------------
// Kernel 2: Gaussian resolution filter + circular conv along n, fp32 -> bf16
// ---------------------------------------------------------------------------
__global__ __launch_bounds__(256)
void conv_kernel(const float* __restrict__ lm_raw, __hip_bfloat16* __restrict__ lm)
{
    __shared__ float row[N_IN];
    __shared__ float fw[FILT];
    const int tid = threadIdx.x;
    const int p   = blockIdx.x;

    if (tid < FILT) {
        float t = (tid - PAD) * (2.0f / FILT);
        float u = t * 10.0f;            // t / sigma0 (sigma0 = 0.1)
        fw[tid] = expf(-0.5f * u * u);
    }
    reinterpret_cast<float4*>(row)[tid] =
        reinterpret_cast<const float4*>(lm_raw + (size_t)p * N_IN)[tid];
    __syncthreads();

    float fsum = 0.f;
#pragma unroll
    for (int f = 0; f < FILT; f++) fsum += fw[f];
    const float inv = 1.0f / fsum;

    const int n0 = tid * 4;
    float o[4] = {0.f, 0.f, 0.f, 0.f};
#pragma unroll
    for (int f = 0; f < FILT; f++) {
        const float w = fw[f];
#pragma unroll
        for (int j = 0; j < 4; j++)
            o[j] += w * row[(n0 + j + f - PAD) & (N_IN - 1)];
    }
    ushort4 ov;
    ov.x = f2bf(o[0] * inv);
    ov.y = f2bf(o[1] * inv);
    ov.z = f2bf(o[2] * inv);
    ov.w = f2bf(o[3] * inv);
    reinterpret_cast<ushort4*>(lm + (size_t)p * N_IN)[tid] = ov;
}

// ---------------------------------------------------------------------------
// Kernel 3: GEMM  C[M,N] = A[M,K] * B[N,K]^T
// r5-proven loop: 256x128 tile, BK=32, 512 thr (8 waves 4Mx2N), wave 64x64
// (acc 4x4), 3-deep LDS ring (72KB -> 2 blocks/CU), counted vmcnt(3),
// both-sides swizzle involution key=(row>>1)&3, T1 XCD swizzle, setprio.
// NEW: LDS-transposed float4 epilogue — after the loop (ring LDS dead, one
// __syncthreads), each wave round-trips its 64x64 fp32 tile through its
// private 8KB LDS region in 2 passes, storing 16 global_store_dwordx4 per
// thread (vs 128 scalar dword) with 256B-contiguous segments.
// ---------------------------------------------------------------------------
__global__ __launch_bounds__(512, 4)
void gemm_bt3(const __hip_bfloat16* __restrict__ A,
              const __hip_bfloat16* __restrict__ B,
              float* __restrict__ C,
              int M, int N, int K)
{
    constexpr int BK = 32;                  // K-tile; rows are 64B (4 x 16B slots)
    __shared__ char smem[3][24576];         // ring: A[256][32] (16K) | B[128][32] (8K)

    const int tid = threadIdx.x;
    const int l   = tid & 63;
    const int w   = tid >> 6;    // 0..7
    const int wm  = w >> 1;      // 0..3  (M direction)
    const int wn  = w & 1;       // 0..1  (N direction)

    // T1: bijective XCD swizzle (nwg=512 divisible by 8)
    const int o    = blockIdx.x;
    const int lin  = (o & 7) * (gridDim.x >> 3) + (o >> 3);
    const int tn   = lin & 7;          // N/128 = 8
    const int tm   = lin >> 3;         // M/256 = 64
    const size_t bm = (size_t)tm * 256;
    const size_t bn = (size_t)tn * 128;

    // ---- staging geometry (per-lane global source, pre-swizzled) ----
    const int srow = w * 16 + (l >> 2);
    const int scol = 16 * ((l & 3) ^ ((l >> 3) & 3));
    const char* gA = (const char*)(A + (bm + srow) * (size_t)K) + scol;
    const char* gB = (const char*)(B + (bn + srow) * (size_t)K) + scol;
    const size_t rowstep = (size_t)128 * K * 2;     // +128 rows (bytes)

#define STAGE(t, b) do {                                                        \
    const char* a0_ = gA + (size_t)(t) * (BK * 2);                              \
    const char* b0_ = gB + (size_t)(t) * (BK * 2);                              \
    char* La_ = &smem[(b)][0]     + w * 1024;                                   \
    char* Lb_ = &smem[(b)][16384] + w * 1024;                                   \
    __builtin_amdgcn_global_load_lds(GLB(a0_),           LDSP(La_),        16, 0, 0); \
    __builtin_amdgcn_global_load_lds(GLB(a0_ + rowstep), LDSP(La_ + 8192), 16, 0, 0); \
    __builtin_amdgcn_global_load_lds(GLB(b0_),           LDSP(Lb_),        16, 0, 0); \
} while (0)

    // ---- fragment-read geometry (swizzled ds_read, same involution) ----
    const int lr = l & 15;
    const int kb = l >> 4;                               // k-block of 8 elems
    const int rslot = 16 * (kb ^ ((lr >> 1) & 3));
    const int abase = (wm * 64 + lr) * 64 + rslot;           // + m*1024
    const int bbase = 16384 + (wn * 64 + lr) * 64 + rslot;   // + n*1024

    f32x4 acc[4][4] = {};

    const int NT = K / BK;                               // 32

    STAGE(0, 0);
    STAGE(1, 1);

    int buf = 0;
    for (int t = 0; t < NT; ++t) {
        asm volatile("s_waitcnt lgkmcnt(0)" ::: "memory");
        if (t < NT - 1) asm volatile("s_waitcnt vmcnt(3)" ::: "memory");
        else            asm volatile("s_waitcnt vmcnt(0)" ::: "memory");
        __builtin_amdgcn_s_barrier();
        asm volatile("" ::: "memory");   // nothing crosses the barrier

        {
            const int t2 = t + 2;
            if (t2 < NT) {
                int b2 = buf + 2; if (b2 >= 3) b2 -= 3;
                STAGE(t2, b2);
            }
        }

        const char* Sb = &smem[buf][0];
        bf16x8 afr[4], bfr[4];
#pragma unroll
        for (int n = 0; n < 4; n++) bfr[n] = *(const bf16x8*)(Sb + bbase + n * 1024);
#pragma unroll
        for (int m = 0; m < 4; m++) afr[m] = *(const bf16x8*)(Sb + abase + m * 1024);

        __builtin_amdgcn_s_setprio(1);
#pragma unroll
        for (int m = 0; m < 4; m++)
#pragma unroll
            for (int n = 0; n < 4; n++)
                acc[m][n] = __builtin_amdgcn_mfma_f32_16x16x32_bf16(afr[m], bfr[n], acc[m][n], 0, 0, 0);
        __builtin_amdgcn_s_setprio(0);

        if (++buf == 3) buf = 0;
    }
#undef STAGE

    // ---- epilogue: LDS-transposed, coalesced float4 stores ----
    // Ring LDS is dead; wave-private 8KB regions (8 x 8KB = 64KB <= 72KB).
    // Two passes of 32 rows: write acc scalars (layout col=lane&15,
    // row=(lane>>4)*4+reg [m89/m91]), read back float4-per-lane, store
    // dwordx4 with 256B-contiguous row segments.
    __syncthreads();   // all waves' ring reads complete before scribbling

    char* tb = &smem[0][0] + w * 8192;
    const int crow = (l >> 4) * 4;
    const int ccol = l & 15;
#pragma unroll
    for (int p = 0; p < 2; ++p) {
#pragma unroll
        for (int i = 0; i < 2; ++i)
#pragma unroll
            for (int n = 0; n < 4; ++n)
#pragma unroll
                for (int r = 0; r < 4; ++r)
                    *reinterpret_cast<float*>(tb + (i * 16 + crow + r) * 256
                                                 + (n * 16 + ccol) * 4)
                        = acc[2 * p + i][n][r];
        // per-wave in-order DS + compiler lgkm orders write->read (same object)
#pragma unroll
        for (int i = 0; i < 8; ++i) {
            const int lr2 = i * 4 + (l >> 4);
            const float4 v = *reinterpret_cast<const float4*>(tb + lr2 * 256 + (l & 15) * 16);
            const size_t row = bm + wm * 64 + p * 32 + lr2;
            const size_t col = bn + wn * 64 + (l & 15) * 4;
            *reinterpret_cast<float4*>(&C[row * N + col]) = v;
        }
    }
}

// ---------------------------------------------------------------------------
extern "C" void kernel_launch(void* const* d_in, const int* in_sizes, int n_in,
                              void* d_out, int out_size, void* d_ws, size_t ws_size,
                              hipStream_t stream) {
    const float* x      = (const float*)d_in[0];   // [M, 1024] fp32
    const float* lm_raw = (const float*)d_in[1];   // [32, 32, 1024] fp32
    float* out = (float*)d_out;                    // [M, 32, 32] fp32

    const int M = in_sizes[0] / N_IN;              // 16384

    // workspace layout: xn bf16 [M,1024] (32 MiB) | lm bf16 [1024,1024] (2 MiB)
    __hip_bfloat16* xn = (__hip_bfloat16*)d_ws;
    __hip_bfloat16* lm = (__hip_bfloat16*)((char*)d_ws + (size_t)M * N_IN * 2);

    normalize_kernel<<<M / 4, 256, 0, stream>>>(x, xn);
    conv_kernel<<<N_P, 256, 0, stream>>>(lm_raw, lm);

    const int nblk = (M / 256) * (N_P / 128);      // 64 * 8 = 512
    gemm_bt3<<<nblk, dim3(512), 0, stream>>>(xn, lm, out, M, N_P, N_IN);
}

// Round 16
// 64.958 us; speedup vs baseline: 1.2195x; 1.0103x over previous
//
#include <hip/hip_runtime.h>
#include <hip/hip_bf16.h>

// Problem dims (fixed by reference)
#define N_IN   1024     // K
#define N_P    1024     // N (= 32*32 lifted grid)
#define FILT   33
#define PAD    16

typedef __attribute__((ext_vector_type(8))) __bf16 bf16x8;
typedef __attribute__((ext_vector_type(4))) float  f32x4;

#define GLB(p) ((const __attribute__((address_space(1))) unsigned int*)(p))
#define LDSP(p) ((__attribute__((address_space(3))) unsigned int*)(p))

__device__ __forceinline__ unsigned short f2bf(float f) {
    union { __hip_bfloat16 h; unsigned short u; } cv;
    cv.h = __float2bfloat16(f);
    return cv.u;
}

// ---------------------------------------------------------------------------
// Kernel 1: per-row demean + std-normalize, fp32 -> bf16 (r1-proven, ~BW floor)
// ---------------------------------------------------------------------------
__global__ __launch_bounds__(256)
void normalize_kernel(const float* __restrict__ x, __hip_bfloat16* __restrict__ xn)
{
    const int lane = threadIdx.x & 63;
    const int row  = blockIdx.x * 4 + (threadIdx.x >> 6);

    const float4* xr = reinterpret_cast<const float4*>(x + (size_t)row * N_IN);
    float4 v[4];
    float s = 0.f, s2 = 0.f;
#pragma unroll
    for (int i = 0; i < 4; i++) {
        v[i] = xr[i * 64 + lane];
        s  += v[i].x + v[i].y + v[i].z + v[i].w;
        s2 += v[i].x * v[i].x + v[i].y * v[i].y + v[i].z * v[i].z + v[i].w * v[i].w;
    }
#pragma unroll
    for (int off = 32; off > 0; off >>= 1) {
        s  += __shfl_xor(s,  off, 64);
        s2 += __shfl_xor(s2, off, 64);
    }
    const float mu  = s * (1.0f / N_IN);
    const float var = fmaxf(s2 * (1.0f / N_IN) - mu * mu, 0.0f);
    const float inv = 1.0f / (sqrtf(var) + 1e-7f);

    ushort4* outv = reinterpret_cast<ushort4*>(xn + (size_t)row * N_IN);
#pragma unroll
    for (int i = 0; i < 4; i++) {
        ushort4 o;
        o.x = f2bf((v[i].x - mu) * inv);
        o.y = f2bf((v[i].y - mu) * inv);
        o.z = f2bf((v[i].z - mu) * inv);
        o.w = f2bf((v[i].w - mu) * inv);
        outv[i * 64 + lane] = o;
    }
}

// ---------------------------------------------------------------------------
// Kernel 2: Gaussian resolution filter + circular conv along n, fp32 -> bf16
// ---------------------------------------------------------------------------
__global__ __launch_bounds__(256)
void conv_kernel(const float* __restrict__ lm_raw, __hip_bfloat16* __restrict__ lm)
{
    __shared__ float row[N_IN];
    __shared__ float fw[FILT];
    const int tid = threadIdx.x;
    const int p   = blockIdx.x;

    if (tid < FILT) {
        float t = (tid - PAD) * (2.0f / FILT);
        float u = t * 10.0f;            // t / sigma0 (sigma0 = 0.1)
        fw[tid] = expf(-0.5f * u * u);
    }
    reinterpret_cast<float4*>(row)[tid] =
        reinterpret_cast<const float4*>(lm_raw + (size_t)p * N_IN)[tid];
    __syncthreads();

    float fsum = 0.f;
#pragma unroll
    for (int f = 0; f < FILT; f++) fsum += fw[f];
    const float inv = 1.0f / fsum;

    const int n0 = tid * 4;
    float o[4] = {0.f, 0.f, 0.f, 0.f};
#pragma unroll
    for (int f = 0; f < FILT; f++) {
        const float w = fw[f];
#pragma unroll
        for (int j = 0; j < 4; j++)
            o[j] += w * row[(n0 + j + f - PAD) & (N_IN - 1)];
    }
    ushort4 ov;
    ov.x = f2bf(o[0] * inv);
    ov.y = f2bf(o[1] * inv);
    ov.z = f2bf(o[2] * inv);
    ov.w = f2bf(o[3] * inv);
    reinterpret_cast<ushort4*>(lm + (size_t)p * N_IN)[tid] = ov;
}

// ---------------------------------------------------------------------------
// Kernel 3: GEMM  C[M,N] = A[M,K] * B[N,K]^T — faithful m201-template phases.
// r11 base: 256x256 tile, BK=32, 512 thr (8 waves 2Mx4N), wave 128x64,
// acc[8][4], 3-ring (96KB), swizzle key=(row>>1)&3, T1, setprio, scalar epi.
// Template levers:
//  - per K-tile opening gate {lgkm(0); COUNTED vmcnt(4); barrier} — never
//    drains to 0 mid-loop (vmcnt(0) only on final tile)  [T4, m218]
//  - 2 phases/K-tile, each {ds_read subtile -> barrier -> own-lgkm(0) ->
//    setprio(1) 16 MFMA setprio(0) -> barrier}  [T3, m233]
//  - staging distributed: 2 A-gloads in ph0, 2 B-gloads in ph1  [m201]
// r15 BUGFIX: phase-1 A-read offset is +4096 bytes (64 rows, the wave's own
// m4-7 half: row = wm*128 + 64 + m*16), NOT +8192 (which crossed into the
// other wave's strip / the B region -> absmax 3.0).
// ---------------------------------------------------------------------------
__global__ __launch_bounds__(512, 2)
void gemm_tpl(const __hip_bfloat16* __restrict__ A,
              const __hip_bfloat16* __restrict__ B,
              float* __restrict__ C,
              int M, int N, int K)
{
    constexpr int BK = 32;                  // K-tile; rows are 64B (4 x 16B slots)
    __shared__ char smem[3][32768];         // ring: A[256][64B] @0 | B[256][64B] @16384

    const int tid = threadIdx.x;
    const int l   = tid & 63;
    const int w   = tid >> 6;    // 0..7
    const int wm  = w >> 2;      // 0..1  (M direction, 128 rows)
    const int wn  = w & 3;       // 0..3  (N direction, 64 cols)

    // T1: bijective XCD swizzle (nwg=256 divisible by 8)
    const int o    = blockIdx.x;
    const int lin  = (o & 7) * (gridDim.x >> 3) + (o >> 3);
    const int tn   = lin & 3;          // N/256 = 4
    const int tm   = lin >> 2;         // M/256 = 64
    const size_t bm = (size_t)tm * 256;
    const size_t bn = (size_t)tn * 256;

    // ---- staging geometry (per-lane global source, pre-swizzled) ----
    const int srow = w * 16 + (l >> 2);
    const int scol = 16 * ((l & 3) ^ ((l >> 3) & 3));
    const char* gA = (const char*)(A + (bm + srow) * (size_t)K) + scol;
    const char* gB = (const char*)(B + (bn + srow) * (size_t)K) + scol;
    const size_t rowstep = (size_t)128 * K * 2;     // +128 rows (bytes)

#define STAGE_A2(t, b) do {                                                     \
    const char* a0_ = gA + (size_t)(t) * (BK * 2);                              \
    char* La_ = &smem[(b)][0] + w * 1024;                                       \
    __builtin_amdgcn_global_load_lds(GLB(a0_),           LDSP(La_),        16, 0, 0); \
    __builtin_amdgcn_global_load_lds(GLB(a0_ + rowstep), LDSP(La_ + 8192), 16, 0, 0); \
} while (0)
#define STAGE_B2(t, b) do {                                                     \
    const char* b0_ = gB + (size_t)(t) * (BK * 2);                              \
    char* Lb_ = &smem[(b)][16384] + w * 1024;                                   \
    __builtin_amdgcn_global_load_lds(GLB(b0_),           LDSP(Lb_),        16, 0, 0); \
    __builtin_amdgcn_global_load_lds(GLB(b0_ + rowstep), LDSP(Lb_ + 8192), 16, 0, 0); \
} while (0)

#define BAR() do { asm volatile("" ::: "memory");                  \
                   __builtin_amdgcn_s_barrier();                   \
                   asm volatile("" ::: "memory"); } while (0)

    // ---- fragment-read geometry (swizzled ds_read, same involution) ----
    const int lr = l & 15;
    const int kb = l >> 4;                               // 16B k-slot
    const int rslot = 16 * (kb ^ ((lr >> 1) & 3));
    const int abase = (wm * 128 + lr) * 64 + rslot;          // + m*1024
    const int bbase = 16384 + (wn * 64 + lr) * 64 + rslot;   // + n*1024

    f32x4 acc[8][4] = {};
    const int NT = K / BK;                               // 32

    // prologue: tiles 0 and 1 fully staged
    STAGE_A2(0, 0); STAGE_B2(0, 0);
    STAGE_A2(1, 1); STAGE_B2(1, 1);

    int buf = 0;
    for (int t = 0; t < NT; ++t) {
        // ---- opening gate: buf t ready for every wave ----
        asm volatile("s_waitcnt lgkmcnt(0)" ::: "memory");  // my t-1 reads drained
        if (t < NT - 1) asm volatile("s_waitcnt vmcnt(4)" ::: "memory"); // counted, never 0
        else            asm volatile("s_waitcnt vmcnt(0)" ::: "memory"); // final tile only
        BAR();

        const char* S = &smem[buf][0];
        int b2 = buf + 2; if (b2 >= 3) b2 -= 3;
        bf16x8 bfr[4], afr[4];

        // ---- phase 0: read (bfr, afr m0-3); stage A(t+2); MFMA m0-3 ----
#pragma unroll
        for (int n = 0; n < 4; n++) bfr[n] = *(const bf16x8*)(S + bbase + n * 1024);
#pragma unroll
        for (int m = 0; m < 4; m++) afr[m] = *(const bf16x8*)(S + abase + m * 1024);
        if (t + 2 < NT) STAGE_A2(t + 2, b2);
        BAR();
        asm volatile("s_waitcnt lgkmcnt(0)" ::: "memory");
        __builtin_amdgcn_s_setprio(1);
#pragma unroll
        for (int m = 0; m < 4; m++)
#pragma unroll
            for (int n = 0; n < 4; n++)
                acc[m][n] = __builtin_amdgcn_mfma_f32_16x16x32_bf16(afr[m], bfr[n], acc[m][n], 0, 0, 0);
        __builtin_amdgcn_s_setprio(0);
        BAR();

        // ---- phase 1: read (afr m4-7, rows wm*128+64..127); stage B(t+2) ----
#pragma unroll
        for (int m = 0; m < 4; m++) afr[m] = *(const bf16x8*)(S + abase + 4096 + m * 1024);
        if (t + 2 < NT) STAGE_B2(t + 2, b2);
        BAR();
        asm volatile("s_waitcnt lgkmcnt(0)" ::: "memory");
        __builtin_amdgcn_s_setprio(1);
#pragma unroll
        for (int m = 0; m < 4; m++)
#pragma unroll
            for (int n = 0; n < 4; n++)
                acc[m + 4][n] = __builtin_amdgcn_mfma_f32_16x16x32_bf16(afr[m], bfr[n], acc[m + 4][n], 0, 0, 0);
        __builtin_amdgcn_s_setprio(0);
        // no closing barrier: next tile's opening gate serves

        if (++buf == 3) buf = 0;
    }
#undef STAGE_A2
#undef STAGE_B2
#undef BAR

    // epilogue: C/D layout col = lane&15, row = (lane>>4)*4 + reg  [m89/m91]
    const int crow = (l >> 4) * 4;
    const int ccol = l & 15;
#pragma unroll
    for (int m = 0; m < 8; m++)
#pragma unroll
        for (int n = 0; n < 4; n++) {
#pragma unroll
            for (int r = 0; r < 4; r++) {
                const size_t row = bm + wm * 128 + m * 16 + crow + r;
                const size_t col = bn + wn * 64 + n * 16 + ccol;
                C[row * N + col] = acc[m][n][r];
            }
        }
}

// ---------------------------------------------------------------------------
extern "C" void kernel_launch(void* const* d_in, const int* in_sizes, int n_in,
                              void* d_out, int out_size, void* d_ws, size_t ws_size,
                              hipStream_t stream) {
    const float* x      = (const float*)d_in[0];   // [M, 1024] fp32
    const float* lm_raw = (const float*)d_in[1];   // [32, 32, 1024] fp32
    float* out = (float*)d_out;                    // [M, 32, 32] fp32

    const int M = in_sizes[0] / N_IN;              // 16384

    // workspace layout: xn bf16 [M,1024] (32 MiB) | lm bf16 [1024,1024] (2 MiB)
    __hip_bfloat16* xn = (__hip_bfloat16*)d_ws;
    __hip_bfloat16* lm = (__hip_bfloat16*)((char*)d_ws + (size_t)M * N_IN * 2);

    normalize_kernel<<<M / 4, 256, 0, stream>>>(x, xn);
    conv_kernel<<<N_P, 256, 0, stream>>>(lm_raw, lm);

    const int nblk = (M / 256) * (N_P / 256);      // 64 * 4 = 256
    gemm_tpl<<<nblk, dim3(512), 0, stream>>>(xn, lm, out, M, N_P, N_IN);
}